// Round 7
// baseline (340.398 us; speedup 1.0000x reference)
//
#include <hip/hip_runtime.h>

// B=2, H=W=512, 21 classes, 11x11 window, 4x blur. H,W % 4 == 0 -> pad=(0,0),
// avg-pool is exact 4x4 mean, post-upsample crop is identity.
// unary (conv3x3) is NEVER materialized: recomputed from x (12 MB) in each step
// instead of re-reading a 44 MB buffer. kc is stored fp16 (values in [0,2.6]).
#define NCH 21
#define HWP (1 << 14)   // 128*128
#define KS 11
#define KK 121
// pac tiling: pooled tile 32x8, thread = 4-px strip x 1 ch, 8-ch groups, 512 thr
#define PTW 32
#define PTH 8
#define LROW 48                // padded cols (42 used); row shift 48%32=16 -> <=2-way
#define LHGT 18
#define LPLANE (LROW * LHGT)   // 864 floats

typedef _Float16 half4 __attribute__((ext_vector_type(4)));

// ---- conv3x3 patch loader: rows y-1..y+1, cols 4*px-1..4*px+4, zero-padded ----
__device__ __forceinline__ void load_patch(const float* __restrict__ x, int b, int y,
                                           int xq, float p[3][3][6]) {
#pragma unroll
    for (int ch = 0; ch < 3; ++ch) {
        const float* xp = x + (((size_t)(b * 3 + ch)) << 18);
#pragma unroll
        for (int rr = 0; rr < 3; ++rr) {
            int yy = y + rr - 1;
            if ((unsigned)yy >= 512u) {
#pragma unroll
                for (int j = 0; j < 6; ++j) p[ch][rr][j] = 0.f;
            } else {
                const float* row = xp + (yy << 9);
                float4 v = *(const float4*)(row + xq);
                p[ch][rr][1] = v.x; p[ch][rr][2] = v.y; p[ch][rr][3] = v.z; p[ch][rr][4] = v.w;
                p[ch][rr][0] = (xq > 0) ? row[xq - 1] : 0.f;
                p[ch][rr][5] = (xq + 4 < 512) ? row[xq + 4] : 0.f;
            }
        }
    }
}

__device__ __forceinline__ void conv4(const float p[3][3][6], const float* __restrict__ w,
                                      const float* __restrict__ bias, int o,
                                      float& a0, float& a1, float& a2, float& a3) {
    const float* wp = w + o * 27;
    float bz = bias[o];
    a0 = bz; a1 = bz; a2 = bz; a3 = bz;
#pragma unroll
    for (int ch = 0; ch < 3; ++ch)
#pragma unroll
        for (int rr = 0; rr < 3; ++rr) {
            float w0 = wp[ch * 9 + rr * 3 + 0];
            float w1 = wp[ch * 9 + rr * 3 + 1];
            float w2 = wp[ch * 9 + rr * 3 + 2];
            const float* pr = p[ch][rr];
            a0 += w0 * pr[0] + w1 * pr[1] + w2 * pr[2];
            a1 += w0 * pr[1] + w1 * pr[2] + w2 * pr[3];
            a2 += w0 * pr[2] + w1 * pr[3] + w2 * pr[4];
            a3 += w0 * pr[3] + w1 * pr[4] + w2 * pr[5];
        }
}

// ---- init: qb = pool4(softmax(conv3x3(x))) ; no unary store ----
__global__ __launch_bounds__(256) void k_init_q(const float* __restrict__ x,
                                                const float* __restrict__ w,
                                                const float* __restrict__ bias,
                                                float* __restrict__ qb) {
    int idx = blockIdx.x * 256 + threadIdx.x;   // 0..131071
    int r = idx & 3;
    int px = (idx >> 2) & 127;
    int py = (idx >> 9) & 127;
    int b = idx >> 16;
    int y = 4 * py + r;
    int xq = px << 2;

    float p[3][3][6];
    load_patch(x, b, y, xq, p);

    float a[NCH][4];
    for (int o = 0; o < NCH; ++o)
        conv4(p, w, bias, o, a[o][0], a[o][1], a[o][2], a[o][3]);

    float qsum[NCH];
#pragma unroll
    for (int c = 0; c < NCH; ++c) qsum[c] = 0.f;
#pragma unroll
    for (int i2 = 0; i2 < 4; ++i2) {
        float m = a[0][i2];
#pragma unroll
        for (int c = 1; c < NCH; ++c) m = fmaxf(m, a[c][i2]);
        float s = 0.f;
#pragma unroll
        for (int c = 0; c < NCH; ++c) { float e = __expf(a[c][i2] - m); a[c][i2] = e; s += e; }
        float inv = 1.0f / s;
#pragma unroll
        for (int c = 0; c < NCH; ++c) qsum[c] += a[c][i2] * inv;
    }
#pragma unroll
    for (int c = 0; c < NCH; ++c) {
        float v = qsum[c];
        v += __shfl_xor(v, 1);
        v += __shfl_xor(v, 2);
        if (r == 0) qb[(((size_t)(b * NCH + c)) << 14) + (py << 7) + px] = v * 0.0625f;
    }
}

// ---------------- pooled RGB ----------------
__global__ __launch_bounds__(256) void k_pool_rgb(const float* __restrict__ x,
                                                  float* __restrict__ prgb) {
    int idx = blockIdx.x * 256 + threadIdx.x;   // [b][3][128][128]
    int p = idx & (HWP - 1);
    int ch = (idx >> 14) % 3;
    int b = idx / (3 * HWP);
    int py = p >> 7, px = p & 127;
    const float* xp = x + (((size_t)(b * 3 + ch)) << 18);
    float s = 0.f;
#pragma unroll
    for (int r = 0; r < 4; ++r) {
        const float4 v = *(const float4*)(xp + (((4 * py + r) << 9) + 4 * px));
        s += v.x + v.y + v.z + v.w;
    }
    prgb[idx] = s * 0.0625f;
}

// ---------------- kc (fp16) = pw0*exp(-.5 s_bil) + pw1*exp(-.5 s_spat) ----------------
__global__ __launch_bounds__(256) void k_build_kc(const float* __restrict__ prgb,
                                                  const float* __restrict__ pw,
                                                  _Float16* __restrict__ kc) {
    int idx = blockIdx.x * 256 + threadIdx.x;   // [b][j][p]
    int p = idx & (HWP - 1);
    int jj = idx >> 14;                          // 0..241
    int b = (jj >= KK) ? 1 : 0;
    int j = jj - KK * b;
    int dy = j / KS, dx = j - dy * KS;
    int py = p >> 7, px = p & 127;
    float pw0 = pw[0], pw1 = pw[1];

    const float inv13 = 1.0f / 13.0f;
    float fy = (4.f * py + 1.5f) * (1.0f / 80.0f);
    float fx = (4.f * px + 1.5f) * (1.0f / 80.0f);
    const float* pb = prgb + (size_t)b * 3 * HWP;
    float r0 = pb[p] * inv13;
    float g0 = pb[HWP + p] * inv13;
    float b0 = pb[2 * HWP + p] * inv13;
    float sy = (4.f * py + 1.5f) * (1.0f / 3.0f);
    float sx = (4.f * px + 1.5f) * (1.0f / 3.0f);

    int ny = py + dy - 5;
    int nx = px + dx - 5;
    float s1, s2;
    if ((unsigned)ny < 128u && (unsigned)nx < 128u) {
        int np = (ny << 7) + nx;
        float r2 = pb[np] * inv13;
        float g2 = pb[HWP + np] * inv13;
        float b2 = pb[2 * HWP + np] * inv13;
        float dya = fy - (4.f * ny + 1.5f) * (1.0f / 80.0f);
        float dxa = fx - (4.f * nx + 1.5f) * (1.0f / 80.0f);
        float dr = r0 - r2, dg = g0 - g2, db = b0 - b2;
        s1 = dya * dya + dxa * dxa + dr * dr + dg * dg + db * db;
        float dys = sy - (4.f * ny + 1.5f) * (1.0f / 3.0f);
        float dxs = sx - (4.f * nx + 1.5f) * (1.0f / 3.0f);
        s2 = dys * dys + dxs * dxs;
    } else {
        s1 = fy * fy + fx * fx + r0 * r0 + g0 * g0 + b0 * b0;  // patch = 0
        s2 = sy * sy + sx * sx;
    }
    kc[idx] = (_Float16)(pw0 * __expf(-0.5f * s1) + pw1 * __expf(-0.5f * s2));
}

// ---- pac: 384 blocks x 512 thr (12 waves/CU); wave = 1 ch x 64 strips; 3 groups of 8 ch.
//      kc traffic/launch = 3 x 7.9 MB (fp16). LDS 27.6 KB, stride 48 (<=2-way). ----
__global__ __launch_bounds__(512) void k_pac(const float* __restrict__ qb,
                                             const _Float16* __restrict__ kc,
                                             float* __restrict__ msgc) {
    int tile = blockIdx.x & 63;                  // 4 x-tiles * 16 y-tiles
    int cg = (blockIdx.x >> 6) % 3;              // channel group of 8
    int b = blockIdx.x / 192;
    int tx0 = (tile & 3) * PTW;
    int ty0 = (tile >> 2) * PTH;
    int c0 = cg * 8;

    __shared__ float lq[8 * LPLANE];             // 27648 B

    const float* qbb = qb + (((size_t)(b * NCH)) << 14);
    for (int i = threadIdx.x; i < 8 * LPLANE; i += 512) {
        int c = i / LPLANE;
        int rem = i - c * LPLANE;
        int ly = rem / LROW;
        int lx = rem - ly * LROW;
        int ch = c0 + c;
        int gy = ty0 + ly - 5, gx = tx0 + lx - 5;
        float v = 0.f;
        if (ch < NCH && lx < 42 && (unsigned)gy < 128u && (unsigned)gx < 128u)
            v = qbb[((size_t)ch << 14) + (gy << 7) + gx];
        lq[i] = v;
    }
    __syncthreads();

    int s = threadIdx.x & 63;
    int cl = threadIdx.x >> 6;                   // 0..7 (== wave id)
    int my = s >> 3;                             // 0..7
    int mx0 = (s & 7) << 2;                      // 0,4,..,28
    int ch = c0 + cl;

    float acc0 = 0.f, acc1 = 0.f, acc2 = 0.f, acc3 = 0.f;
    int p0 = ((ty0 + my) << 7) + tx0 + mx0;
    const _Float16* kcb = kc + (((size_t)(b * KK)) << 14) + p0;
    const float* lbase = lq + cl * LPLANE + mx0;

    for (int dy = 0; dy < KS; ++dy) {
        const float* lp = lbase + (my + dy) * LROW;
        float4 v0 = *(const float4*)(lp + 0);
        float4 v1 = *(const float4*)(lp + 4);
        float4 v2 = *(const float4*)(lp + 8);
        float4 v3 = *(const float4*)(lp + 12);
        float rb[16] = {v0.x, v0.y, v0.z, v0.w, v1.x, v1.y, v1.z, v1.w,
                        v2.x, v2.y, v2.z, v2.w, v3.x, v3.y, v3.z, v3.w};
        const _Float16* kcrow = kcb + (((size_t)(dy * KS)) << 14);
#pragma unroll
        for (int dx = 0; dx < KS; ++dx) {
            half4 k4 = *(const half4*)(kcrow + (((size_t)dx) << 14));
            acc0 += (float)k4.x * rb[dx + 0];
            acc1 += (float)k4.y * rb[dx + 1];
            acc2 += (float)k4.z * rb[dx + 2];
            acc3 += (float)k4.w * rb[dx + 3];
        }
    }
    if (ch < NCH)
        *(float4*)(msgc + (((size_t)(b * NCH + ch)) << 14) + p0) =
            make_float4(acc0, acc1, acc2, acc3);
}

// ---- step: conv recomputed inline; mode 0: qb = pool4(softmax(uw*conv+up4(msg)));
//      mode 1 (final): out = uw*conv + up4(msg) ----
__global__ __launch_bounds__(256) void k_step(const float* __restrict__ x,
                                              const float* __restrict__ w,
                                              const float* __restrict__ bias,
                                              const float* __restrict__ msgc,
                                              const float* __restrict__ uwp,
                                              float* __restrict__ qb,
                                              float* __restrict__ out,
                                              int write_out) {
    int idx = blockIdx.x * 256 + threadIdx.x;   // 0..131071
    int r = idx & 3;
    int px = (idx >> 2) & 127;
    int py = (idx >> 9) & 127;
    int b = idx >> 16;
    int y = 4 * py + r;
    int xq = px << 2;
    float uw = uwp[0];

    float p[3][3][6];
    load_patch(x, b, y, xq, p);

    // bilinear-x4 geometry (verified in rounds 5-6)
    int rA = (r < 2) ? max(py - 1, 0) : py;
    int rB = (r < 2) ? py : min(py + 1, 127);
    float fy = (r == 0) ? 0.625f : (r == 1) ? 0.875f : (r == 2) ? 0.125f : 0.375f;
    int xm1 = max(px - 1, 0), xp1 = min(px + 1, 127);
    int oA = rA << 7, oB = rB << 7;

    const float* mp = msgc + (((size_t)(b * NCH)) << 14);

    float a[NCH][4];
#pragma unroll
    for (int c = 0; c < NCH; ++c) {
        float u0, u1, u2, u3;
        conv4(p, w, bias, c, u0, u1, u2, u3);
        const float* m0 = mp + ((size_t)c << 14);
        float aL = m0[oA + xm1], aM = m0[oA + px], aR = m0[oA + xp1];
        float bL = m0[oB + xm1], bM = m0[oB + px], bR = m0[oB + xp1];
        float cL = aL + (bL - aL) * fy;
        float cM = aM + (bM - aM) * fy;
        float cR = aR + (bR - aR) * fy;
        a[c][0] = uw * u0 + cL + (cM - cL) * 0.625f;
        a[c][1] = uw * u1 + cL + (cM - cL) * 0.875f;
        a[c][2] = uw * u2 + cM + (cR - cM) * 0.125f;
        a[c][3] = uw * u3 + cM + (cR - cM) * 0.375f;
    }

    if (write_out) {
        float* op = out + (((size_t)(b * NCH)) << 18) + (y << 9) + xq;
#pragma unroll
        for (int c = 0; c < NCH; ++c)
            *(float4*)(op + ((size_t)c << 18)) = make_float4(a[c][0], a[c][1], a[c][2], a[c][3]);
        return;
    }

    float qsum[NCH];
#pragma unroll
    for (int c = 0; c < NCH; ++c) qsum[c] = 0.f;
#pragma unroll
    for (int i2 = 0; i2 < 4; ++i2) {
        float m = a[0][i2];
#pragma unroll
        for (int c = 1; c < NCH; ++c) m = fmaxf(m, a[c][i2]);
        float ss = 0.f;
#pragma unroll
        for (int c = 0; c < NCH; ++c) { float e = __expf(a[c][i2] - m); a[c][i2] = e; ss += e; }
        float inv = 1.0f / ss;
#pragma unroll
        for (int c = 0; c < NCH; ++c) qsum[c] += a[c][i2] * inv;
    }
#pragma unroll
    for (int c = 0; c < NCH; ++c) {
        float v = qsum[c];
        v += __shfl_xor(v, 1);
        v += __shfl_xor(v, 2);
        if (r == 0) qb[(((size_t)(b * NCH + c)) << 14) + (py << 7) + px] = v * 0.0625f;
    }
}

extern "C" void kernel_launch(void* const* d_in, const int* in_sizes, int n_in,
                              void* d_out, int out_size, void* d_ws, size_t ws_size,
                              hipStream_t stream) {
    const float* x  = (const float*)d_in[0];
    const float* wb = (const float*)d_in[1];
    const float* bb = (const float*)d_in[2];
    const float* uw = (const float*)d_in[3];
    const float* pw = (const float*)d_in[4];
    float* out = (float*)d_out;

    // Workspace ~13.8 MB (unary eliminated; kc is fp16).
    _Float16* kc = (_Float16*)d_ws;       // 2*121*16384 halfs = 7.93 MB
    float* qb    = (float*)(kc + 3964928);  // 688,128 floats
    float* msgc  = qb + 688128;             // 688,128
    float* prgb  = msgc + 688128;           // 98,304

    k_init_q<<<512, 256, 0, stream>>>(x, wb, bb, qb);
    k_pool_rgb<<<384, 256, 0, stream>>>(x, prgb);
    k_build_kc<<<15488, 256, 0, stream>>>(prgb, pw, kc);

    for (int s = 0; s < 5; ++s) {
        k_pac<<<384, 512, 0, stream>>>(qb, kc, msgc);
        k_step<<<512, 256, 0, stream>>>(x, wb, bb, msgc, uw, qb, out, (s == 4) ? 1 : 0);
    }
}

// Round 8
// 272.889 us; speedup vs baseline: 1.2474x; 1.2474x over previous
//
#include <hip/hip_runtime.h>

// B=2, H=W=512, 21 classes, 11x11 window, 4x blur. H,W % 4 == 0 -> pad=(0,0),
// avg-pool is exact 4x4 mean, post-upsample crop is identity.
// History: r6 = 284 us (pac4 19.7, step ~33). r7 conv-recompute + 512-thr pac
// REGRESSED (340) -> reverted. r8: LDS-staged msgc in k_step + fp16 kc on the
// proven pac4 shape (768 blocks = 3 blocks/CU).
#define NCH 21
#define HWP (1 << 14)   // 128*128
#define KS 11
#define KK 121
// pac v4 tiling: pooled tile 32x8, thread = 4-px strip x 1 ch, 4-ch groups
#define PTW 32
#define PTH 8
#define LROW 48                // padded cols (42 used); 48 % 32 == 16 -> <=2-way b128
#define LHGT 18
#define LPLANE (LROW * LHGT)   // 864 floats

typedef _Float16 half4 __attribute__((ext_vector_type(4)));

// ---- fused: unary = conv3x3(x,w)+b (written); qb = pool4(softmax(unary)) ----
__global__ __launch_bounds__(256) void k_conv_sm(const float* __restrict__ x,
                                                 const float* __restrict__ w,
                                                 const float* __restrict__ bias,
                                                 float* __restrict__ unary,
                                                 float* __restrict__ qb) {
    int idx = blockIdx.x * 256 + threadIdx.x;   // 0..131071
    int r = idx & 3;
    int xqi = (idx >> 2) & 127;
    int py = (idx >> 9) & 127;
    int b = idx >> 16;
    int y = 4 * py + r;
    int xq = xqi << 2;

    float p[3][3][6];
#pragma unroll
    for (int ch = 0; ch < 3; ++ch) {
        const float* xp = x + (((size_t)(b * 3 + ch)) << 18);
#pragma unroll
        for (int rr = 0; rr < 3; ++rr) {
            int yy = y + rr - 1;
            if ((unsigned)yy >= 512u) {
#pragma unroll
                for (int j = 0; j < 6; ++j) p[ch][rr][j] = 0.f;
            } else {
                const float* row = xp + (yy << 9);
                float4 v = *(const float4*)(row + xq);
                p[ch][rr][1] = v.x; p[ch][rr][2] = v.y; p[ch][rr][3] = v.z; p[ch][rr][4] = v.w;
                p[ch][rr][0] = (xq > 0) ? row[xq - 1] : 0.f;
                p[ch][rr][5] = (xq + 4 < 512) ? row[xq + 4] : 0.f;
            }
        }
    }
    float a[NCH][4];
    for (int o = 0; o < NCH; ++o) {
        const float* wp = w + o * 27;
        float bz = bias[o];
        float a0 = bz, a1 = bz, a2 = bz, a3 = bz;
#pragma unroll
        for (int ch = 0; ch < 3; ++ch)
#pragma unroll
            for (int rr = 0; rr < 3; ++rr) {
                float w0 = wp[ch * 9 + rr * 3 + 0];
                float w1 = wp[ch * 9 + rr * 3 + 1];
                float w2 = wp[ch * 9 + rr * 3 + 2];
                const float* pr = p[ch][rr];
                a0 += w0 * pr[0] + w1 * pr[1] + w2 * pr[2];
                a1 += w0 * pr[1] + w1 * pr[2] + w2 * pr[3];
                a2 += w0 * pr[2] + w1 * pr[3] + w2 * pr[4];
                a3 += w0 * pr[3] + w1 * pr[4] + w2 * pr[5];
            }
        *(float4*)(unary + (((size_t)(b * NCH + o)) << 18) + (y << 9) + xq) =
            make_float4(a0, a1, a2, a3);
        a[o][0] = a0; a[o][1] = a1; a[o][2] = a2; a[o][3] = a3;
    }
    float qsum[NCH];
#pragma unroll
    for (int c = 0; c < NCH; ++c) qsum[c] = 0.f;
#pragma unroll
    for (int i2 = 0; i2 < 4; ++i2) {
        float m = a[0][i2];
#pragma unroll
        for (int c = 1; c < NCH; ++c) m = fmaxf(m, a[c][i2]);
        float s = 0.f;
#pragma unroll
        for (int c = 0; c < NCH; ++c) { float e = __expf(a[c][i2] - m); a[c][i2] = e; s += e; }
        float inv = 1.0f / s;
#pragma unroll
        for (int c = 0; c < NCH; ++c) qsum[c] += a[c][i2] * inv;
    }
#pragma unroll
    for (int c = 0; c < NCH; ++c) {
        float v = qsum[c];
        v += __shfl_xor(v, 1);
        v += __shfl_xor(v, 2);
        if (r == 0) qb[(((size_t)(b * NCH + c)) << 14) + (py << 7) + xqi] = v * 0.0625f;
    }
}

// ---------------- pooled RGB ----------------
__global__ __launch_bounds__(256) void k_pool_rgb(const float* __restrict__ x,
                                                  float* __restrict__ prgb) {
    int idx = blockIdx.x * 256 + threadIdx.x;   // [b][3][128][128]
    int p = idx & (HWP - 1);
    int ch = (idx >> 14) % 3;
    int b = idx / (3 * HWP);
    int py = p >> 7, px = p & 127;
    const float* xp = x + (((size_t)(b * 3 + ch)) << 18);
    float s = 0.f;
#pragma unroll
    for (int r = 0; r < 4; ++r) {
        const float4 v = *(const float4*)(xp + (((4 * py + r) << 9) + 4 * px));
        s += v.x + v.y + v.z + v.w;
    }
    prgb[idx] = s * 0.0625f;
}

// ---------------- kc (fp16) = pw0*exp(-.5 s_bil) + pw1*exp(-.5 s_spat) ----------------
__global__ __launch_bounds__(256) void k_build_kc(const float* __restrict__ prgb,
                                                  const float* __restrict__ pw,
                                                  _Float16* __restrict__ kc) {
    int idx = blockIdx.x * 256 + threadIdx.x;   // [b][j][p]
    int p = idx & (HWP - 1);
    int jj = idx >> 14;                          // 0..241
    int b = (jj >= KK) ? 1 : 0;
    int j = jj - KK * b;
    int dy = j / KS, dx = j - dy * KS;
    int py = p >> 7, px = p & 127;
    float pw0 = pw[0], pw1 = pw[1];

    const float inv13 = 1.0f / 13.0f;
    float fy = (4.f * py + 1.5f) * (1.0f / 80.0f);
    float fx = (4.f * px + 1.5f) * (1.0f / 80.0f);
    const float* pb = prgb + (size_t)b * 3 * HWP;
    float r0 = pb[p] * inv13;
    float g0 = pb[HWP + p] * inv13;
    float b0 = pb[2 * HWP + p] * inv13;
    float sy = (4.f * py + 1.5f) * (1.0f / 3.0f);
    float sx = (4.f * px + 1.5f) * (1.0f / 3.0f);

    int ny = py + dy - 5;
    int nx = px + dx - 5;
    float s1, s2;
    if ((unsigned)ny < 128u && (unsigned)nx < 128u) {
        int np = (ny << 7) + nx;
        float r2 = pb[np] * inv13;
        float g2 = pb[HWP + np] * inv13;
        float b2 = pb[2 * HWP + np] * inv13;
        float dya = fy - (4.f * ny + 1.5f) * (1.0f / 80.0f);
        float dxa = fx - (4.f * nx + 1.5f) * (1.0f / 80.0f);
        float dr = r0 - r2, dg = g0 - g2, db = b0 - b2;
        s1 = dya * dya + dxa * dxa + dr * dr + dg * dg + db * db;
        float dys = sy - (4.f * ny + 1.5f) * (1.0f / 3.0f);
        float dxs = sx - (4.f * nx + 1.5f) * (1.0f / 3.0f);
        s2 = dys * dys + dxs * dxs;
    } else {
        s1 = fy * fy + fx * fx + r0 * r0 + g0 * g0 + b0 * b0;  // patch = 0
        s2 = sy * sy + sx * sx;
    }
    kc[idx] = (_Float16)(pw0 * __expf(-0.5f * s1) + pw1 * __expf(-0.5f * s2));
}

// ---- pac v4 (r6 shape): 768 blocks x 256 thr = 3 blocks/CU; thread = 4-px strip x 1 ch;
//      4-ch groups; kc fp16 (traffic 47.6 MB/launch vs 95 fp32). ----
__global__ __launch_bounds__(256) void k_pac4(const float* __restrict__ qb,
                                              const _Float16* __restrict__ kc,
                                              float* __restrict__ msgc) {
    int tile = blockIdx.x & 63;                  // 4 x-tiles * 16 y-tiles
    int cg = (blockIdx.x >> 6) % 6;              // channel group of 4
    int b = blockIdx.x / 384;
    int tx0 = (tile & 3) * PTW;
    int ty0 = (tile >> 2) * PTH;
    int c0 = cg * 4;

    __shared__ float lq[4 * LPLANE];             // 13824 B

    const float* qbb = qb + (((size_t)(b * NCH)) << 14);
    for (int i = threadIdx.x; i < 4 * LPLANE; i += 256) {
        int c = i / LPLANE;
        int rem = i - c * LPLANE;
        int ly = rem / LROW;
        int lx = rem - ly * LROW;
        int ch = c0 + c;
        int gy = ty0 + ly - 5, gx = tx0 + lx - 5;
        float v = 0.f;
        if (ch < NCH && lx < 42 && (unsigned)gy < 128u && (unsigned)gx < 128u)
            v = qbb[((size_t)ch << 14) + (gy << 7) + gx];
        lq[i] = v;
    }
    __syncthreads();

    int s = threadIdx.x & 63;
    int cl = threadIdx.x >> 6;                   // 0..3
    int my = s >> 3;                             // 0..7
    int mx0 = (s & 7) << 2;                      // 0,4,..,28
    int ch = c0 + cl;

    float acc0 = 0.f, acc1 = 0.f, acc2 = 0.f, acc3 = 0.f;
    int p0 = ((ty0 + my) << 7) + tx0 + mx0;
    const _Float16* kcb = kc + (((size_t)(b * KK)) << 14) + p0;
    const float* lbase = lq + cl * LPLANE + mx0;

    for (int dy = 0; dy < KS; ++dy) {
        const float* lp = lbase + (my + dy) * LROW;
        float4 v0 = *(const float4*)(lp + 0);
        float4 v1 = *(const float4*)(lp + 4);
        float4 v2 = *(const float4*)(lp + 8);
        float4 v3 = *(const float4*)(lp + 12);
        float rb[16] = {v0.x, v0.y, v0.z, v0.w, v1.x, v1.y, v1.z, v1.w,
                        v2.x, v2.y, v2.z, v2.w, v3.x, v3.y, v3.z, v3.w};
        const _Float16* kcrow = kcb + (((size_t)(dy * KS)) << 14);
#pragma unroll
        for (int dx = 0; dx < KS; ++dx) {
            half4 k4 = *(const half4*)(kcrow + (((size_t)dx) << 14));
            acc0 += (float)k4.x * rb[dx + 0];
            acc1 += (float)k4.y * rb[dx + 1];
            acc2 += (float)k4.z * rb[dx + 2];
            acc3 += (float)k4.w * rb[dx + 3];
        }
    }
    if (ch < NCH)
        *(float4*)(msgc + (((size_t)(b * NCH + ch)) << 14) + p0) =
            make_float4(acc0, acc1, acc2, acc3);
}

// ---- step: block = pooled row half (py, px0..px0+63); msgc 3-row window staged in LDS.
//      mode 0: qb = pool4(softmax(uw*unary+up4(msg))); mode 1: out = uw*unary+up4(msg) ----
__global__ __launch_bounds__(256) void k_step(const float* __restrict__ unary,
                                              const float* __restrict__ msgc,
                                              const float* __restrict__ uwp,
                                              float* __restrict__ qb,
                                              float* __restrict__ out,
                                              int write_out) {
    int half = blockIdx.x & 1;
    int py = (blockIdx.x >> 1) & 127;
    int b = blockIdx.x >> 8;
    int px0 = half << 6;

    __shared__ float lmsg[NCH * 3 * 66];        // 16632 B

    // stage rows clamp(py-1), py, clamp(py+1), cols clamp(px0-1 .. px0+64)
    const float* mbase = msgc + (((size_t)(b * NCH)) << 14);
    for (int i = threadIdx.x; i < NCH * 198; i += 256) {
        int c = i / 198;
        int rem = i - c * 198;
        int row = rem / 66;
        int j = rem - row * 66;
        int ry = min(max(py - 1 + row, 0), 127);
        int gx = min(max(px0 - 1 + j, 0), 127);
        lmsg[i] = mbase[((size_t)c << 14) + (ry << 7) + gx];
    }
    __syncthreads();

    int r = threadIdx.x & 3;
    int lpx = threadIdx.x >> 2;                  // 0..63
    int px = px0 + lpx;
    int y = 4 * py + r;
    float uw = uwp[0];

    // rows: r<2 -> (py-1,py) fy in {0.625,0.875}; r>=2 -> (py,py+1) fy in {0.125,0.375}
    int iA = (r < 2) ? 0 : 1;
    int iB = iA + 1;
    float fy = (r == 0) ? 0.625f : (r == 1) ? 0.875f : (r == 2) ? 0.125f : 0.375f;

    size_t base = (((size_t)(b * NCH)) << 18) + (y << 9) + (px << 2);
    const float* up = unary + base;

    float a[NCH][4];
#pragma unroll
    for (int c = 0; c < NCH; ++c) {
        float4 u4 = *(const float4*)(up + ((size_t)c << 18));
        const float* lA = lmsg + c * 198 + iA * 66 + lpx;
        const float* lB = lmsg + c * 198 + iB * 66 + lpx;
        float aL = lA[0], aM = lA[1], aR = lA[2];
        float bL = lB[0], bM = lB[1], bR = lB[2];
        float cL = aL + (bL - aL) * fy;
        float cM = aM + (bM - aM) * fy;
        float cR = aR + (bR - aR) * fy;
        a[c][0] = uw * u4.x + cL + (cM - cL) * 0.625f;
        a[c][1] = uw * u4.y + cL + (cM - cL) * 0.875f;
        a[c][2] = uw * u4.z + cM + (cR - cM) * 0.125f;
        a[c][3] = uw * u4.w + cM + (cR - cM) * 0.375f;
    }

    if (write_out) {
        float* op = out + base;
#pragma unroll
        for (int c = 0; c < NCH; ++c)
            *(float4*)(op + ((size_t)c << 18)) = make_float4(a[c][0], a[c][1], a[c][2], a[c][3]);
        return;
    }

    float qsum[NCH];
#pragma unroll
    for (int c = 0; c < NCH; ++c) qsum[c] = 0.f;
#pragma unroll
    for (int i2 = 0; i2 < 4; ++i2) {
        float m = a[0][i2];
#pragma unroll
        for (int c = 1; c < NCH; ++c) m = fmaxf(m, a[c][i2]);
        float ss = 0.f;
#pragma unroll
        for (int c = 0; c < NCH; ++c) { float e = __expf(a[c][i2] - m); a[c][i2] = e; ss += e; }
        float inv = 1.0f / ss;
#pragma unroll
        for (int c = 0; c < NCH; ++c) qsum[c] += a[c][i2] * inv;
    }
#pragma unroll
    for (int c = 0; c < NCH; ++c) {
        float v = qsum[c];
        v += __shfl_xor(v, 1);
        v += __shfl_xor(v, 2);
        if (r == 0) qb[(((size_t)(b * NCH + c)) << 14) + (py << 7) + px] = v * 0.0625f;
    }
}

extern "C" void kernel_launch(void* const* d_in, const int* in_sizes, int n_in,
                              void* d_out, int out_size, void* d_ws, size_t ws_size,
                              hipStream_t stream) {
    const float* x  = (const float*)d_in[0];
    const float* wb = (const float*)d_in[1];
    const float* bb = (const float*)d_in[2];
    const float* uw = (const float*)d_in[3];
    const float* pw = (const float*)d_in[4];
    float* out = (float*)d_out;

    // Footprint ~57.5 MB (< proven 65.8 MB). prgb aliases msgc (dead after build_kc).
    float* ws    = (float*)d_ws;
    float* unary = ws;                            // 11,010,048 floats
    _Float16* kc = (_Float16*)(unary + 11010048); // 3,964,928 halfs
    float* qb    = (float*)(kc + 3964928);        // 688,128 floats
    float* msgc  = qb + 688128;                   // 688,128
    float* prgb  = msgc;                          // 98,304 (alias)

    k_conv_sm<<<512, 256, 0, stream>>>(x, wb, bb, unary, qb);
    k_pool_rgb<<<384, 256, 0, stream>>>(x, prgb);
    k_build_kc<<<15488, 256, 0, stream>>>(prgb, pw, kc);

    for (int s = 0; s < 5; ++s) {
        k_pac4<<<768, 256, 0, stream>>>(qb, kc, msgc);
        k_step<<<512, 256, 0, stream>>>(unary, msgc, uw, qb, out, (s == 4) ? 1 : 0);
    }
}